// Round 7
// baseline (710.430 us; speedup 1.0000x reference)
//
#include <hip/hip_runtime.h>
#include <cstdint>

typedef __attribute__((ext_vector_type(4))) float f32x4;
typedef __attribute__((ext_vector_type(8))) short bf16x8;
typedef __attribute__((ext_vector_type(4))) short bf16x4;

#define DEV static __device__ __forceinline__

// round-to-nearest-even f32 -> bf16 (bit pattern)
DEV unsigned short f2bf(float f) {
    union { float f; unsigned int u; } v; v.f = f;
    unsigned int u = v.u;
    return (unsigned short)((u + 0x7FFFu + ((u >> 16) & 1u)) >> 16);
}

// async global->LDS 16B per lane; LDS dest = wave-uniform base + lane*16
DEV void async_cp16(const void* g, void* l) {
    __builtin_amdgcn_global_load_lds(
        (const __attribute__((address_space(1))) unsigned int*)g,
        (__attribute__((address_space(3))) unsigned int*)l,
        16, 0, 0);
}

// stage one 128x64 bf16 half-tile (16KB): 512 threads x 2 chunks of 16B.
// linear LDS dest, inverse-swizzled global source (involution: slot^=(row&7)).
DEV void stage_half(const unsigned short* __restrict__ g, long kofs,
                    unsigned short* l, int tid, int gpitch) {
#pragma unroll
    for (int i = 0; i < 2; ++i) {
        int c = i * 512 + tid;
        int row = c >> 3;
        int ss = (c & 7) ^ (row & 7);
        async_cp16(g + (long)row * gpitch + kofs + ss * 8,
                   l + (i * 512 + (tid & 448)) * 8);
    }
}

// swizzled LDS fragment read (bank-conflict-free pair of the stage swizzle)
DEV bf16x8 ldsrd(const unsigned short* base, int r, int q) {
    return *(const bf16x8*)&base[r * 64 + ((q ^ (r & 7)) << 3)];
}

// ---------------------------------------------------------------------------
// 256x256 8-wave GEMM core. BK=64, NT K-tiles, dbuf'd 128KB LDS.
// lds layout (ushort idx): A(d,h) = (d*2+h)*8192 ; B(d,h) = 32768+(d*2+h)*8192
// Wave (wr=wv>>2, wcq=wv&3) owns C rows [wr*128,+128) x cols [wcq*64,+64).
// Software-pipelined fragments: 4 MFMA groups/tile (G0=af0*bf0, G1=af0*bf1,
// G2=af1*bf0, G3=af1*bf1), reads issued >=1 group ahead; compiler emits
// counted lgkmcnt from reg deps (no serial lgkmcnt(0) drains). ONE barrier
// per tile (after G2) with vmcnt(0): all 8 staging loads of tile t+1 were
// issued >=3 phases earlier (ph0(t): A[t+1,h1]+B[t+1]; ph3(t-1): A[t+1,h0]).
// ph3 (post-barrier) pre-reads next tile's G0(kq0) frags, draining under G3.
// Race ledger: fast-wave staging in (bar(t),bar(t+1)) targets t-parity
// buffers only; all reads in that window are (t+1)-parity; t-parity reads
// are reg-complete before bar(t).
// ---------------------------------------------------------------------------
template <int NT>
DEV void gemm256(const unsigned short* __restrict__ gA,
                 const unsigned short* __restrict__ gB,
                 const int gpitch, unsigned short* lds,
                 f32x4 (&acc)[8][4], const int tid) {
    const int lane = tid & 63;
    const int wv = tid >> 6;
    const int wr = wv >> 2;
    const int wcq = wv & 3;
    const int lhi = lane >> 4, llo = lane & 15;
    const int hb = wcq >> 1;           // B half-tile index
    const int br0 = (wcq & 1) * 64;    // B row base within half

#define MG(AF, BF, KQ, RI0, CJ0)                                              \
    _Pragma("unroll") for (int i = 0; i < 4; ++i)                             \
    _Pragma("unroll") for (int j = 0; j < 2; ++j)                             \
        acc[RI0 + i][CJ0 + j] = __builtin_amdgcn_mfma_f32_16x16x32_bf16(      \
            AF[KQ][i], BF[KQ][j], acc[RI0 + i][CJ0 + j], 0, 0, 0);

    // prologue: K-tile 0 (8 loads) + tile 1's A[h0] (2 loads), wait tile 0
    stage_half(gA, 0, lds + 0 * 8192, tid, gpitch);                      // A[0,h0]
    stage_half(gA + (long)128 * gpitch, 0, lds + 1 * 8192, tid, gpitch); // A[0,h1]
    stage_half(gB, 0, lds + 32768 + 0 * 8192, tid, gpitch);              // B[0,h0]
    stage_half(gB + (long)128 * gpitch, 0, lds + 32768 + 1 * 8192, tid, gpitch); // B[0,h1]
    if (NT > 1) {
        stage_half(gA, 64, lds + 2 * 8192, tid, gpitch);                 // A[1,h0]
        asm volatile("s_waitcnt vmcnt(2)" ::: "memory");
    } else {
        asm volatile("s_waitcnt vmcnt(0)" ::: "memory");
    }
    __builtin_amdgcn_s_barrier();
    __builtin_amdgcn_sched_barrier(0);

    bf16x8 af0[2][4], af1[2][4], bf0[2][2], bf1[2][2];

    // pre-read G0(kq0) frags of tile 0
    {
        const unsigned short* lA = lds + wr * 8192;
        const unsigned short* lB = lds + 32768 + hb * 8192;
#pragma unroll
        for (int i = 0; i < 4; ++i) af0[0][i] = ldsrd(lA, i * 16 + llo, lhi);
#pragma unroll
        for (int j = 0; j < 2; ++j) bf0[0][j] = ldsrd(lB, br0 + j * 16 + llo, lhi);
    }

    for (int kt = 0; kt < NT; ++kt) {
        const int cur = kt & 1, nxt = cur ^ 1;
        const unsigned short* lA  = lds + (cur * 2 + wr) * 8192;
        const unsigned short* lB  = lds + 32768 + (cur * 2 + hb) * 8192;
        const unsigned short* lAn = lds + (nxt * 2 + wr) * 8192;
        const unsigned short* lBn = lds + 32768 + (nxt * 2 + hb) * 8192;
        const bool pf1 = (kt + 1 < NT);
        const bool pf2 = (kt + 2 < NT);
        const long k1 = (long)(kt + 1) * 64;
        const long k2 = (long)(kt + 2) * 64;

        // ---- ph0: read af0[kq1]+bf0[kq1]+bf1; stage A[t+1,h1]+B[t+1]; G0 --
#pragma unroll
        for (int i = 0; i < 4; ++i) af0[1][i] = ldsrd(lA, i * 16 + llo, 4 + lhi);
#pragma unroll
        for (int j = 0; j < 2; ++j) bf0[1][j] = ldsrd(lB, br0 + j * 16 + llo, 4 + lhi);
#pragma unroll
        for (int kq = 0; kq < 2; ++kq)
#pragma unroll
            for (int j = 0; j < 2; ++j)
                bf1[kq][j] = ldsrd(lB, br0 + 32 + j * 16 + llo, kq * 4 + lhi);
        if (pf1) {
            stage_half(gA + (long)128 * gpitch, k1, lds + (nxt * 2 + 1) * 8192, tid, gpitch);
            stage_half(gB, k1, lds + 32768 + (nxt * 2 + 0) * 8192, tid, gpitch);
            stage_half(gB + (long)128 * gpitch, k1, lds + 32768 + (nxt * 2 + 1) * 8192, tid, gpitch);
        }
        __builtin_amdgcn_s_setprio(1);
        MG(af0, bf0, 0, 0, 0)
        MG(af0, bf0, 1, 0, 0)
        __builtin_amdgcn_s_setprio(0);

        // ---- ph1: pure compute G1 (bf1 read a phase ago) -----------------
        __builtin_amdgcn_s_setprio(1);
        MG(af0, bf1, 0, 0, 2)
        MG(af0, bf1, 1, 0, 2)
        __builtin_amdgcn_s_setprio(0);

        // ---- ph2: read af1 (kq0 first, self-hides under G2 kq0); G2 ------
#pragma unroll
        for (int kq = 0; kq < 2; ++kq)
#pragma unroll
            for (int i = 0; i < 4; ++i)
                af1[kq][i] = ldsrd(lA, 64 + i * 16 + llo, kq * 4 + lhi);
        __builtin_amdgcn_s_setprio(1);
        MG(af1, bf0, 0, 4, 0)
        MG(af1, bf0, 1, 4, 0)
        __builtin_amdgcn_s_setprio(0);
        asm volatile("s_waitcnt vmcnt(0)" ::: "memory");
        __builtin_amdgcn_s_barrier();
        __builtin_amdgcn_sched_barrier(0);

        // ---- ph3: pre-read next G0(kq0) from nxt; stage A[t+2,h0]; G3 ----
        if (pf1) {
#pragma unroll
            for (int i = 0; i < 4; ++i) af0[0][i] = ldsrd(lAn, i * 16 + llo, lhi);
#pragma unroll
            for (int j = 0; j < 2; ++j) bf0[0][j] = ldsrd(lBn, br0 + j * 16 + llo, lhi);
        }
        if (pf2) stage_half(gA, k2, lds + (cur * 2 + 0) * 8192, tid, gpitch);
        __builtin_amdgcn_s_setprio(1);
        MG(af1, bf1, 0, 4, 2)
        MG(af1, bf1, 1, 4, 2)
        __builtin_amdgcn_s_setprio(0);
    }
#undef MG
}

// ---------------------------------------------------------------------------
// Kernel 0: weight prep.
//  w12t[n][k]: n even -> bf16(w0[k]*w1[k][n/2]), n odd -> bf16(w0[k]*w2[k][n/2])
//  w3t[j][n] = bf16(w3[n][j])   (1024 x 512, n contiguous)
// ---------------------------------------------------------------------------
__global__ void prep_w(const float* __restrict__ w0, const float* __restrict__ w1,
                       const float* __restrict__ w2, const float* __restrict__ w3,
                       unsigned short* __restrict__ w12t, unsigned short* __restrict__ w3t) {
    int t = blockIdx.x * 256 + threadIdx.x;
    if (t < 1048576) {
        int n = t >> 10, k = t & 1023;
        const float* src = (n & 1) ? w2 : w1;
        w12t[t] = f2bf(w0[k] * src[k * 512 + (n >> 1)]);
    } else {
        int idx = t - 1048576;
        int j = idx >> 9, n = idx & 511;
        w3t[idx] = f2bf(w3[n * 1024 + j]);
    }
}

// ---------------------------------------------------------------------------
// Kernel 0b: RMSNorm fold. xb[row][k] = bf16(x[row][k] * rsqrt(mean(x^2)))
// ---------------------------------------------------------------------------
__global__ __launch_bounds__(256)
void prep_x(const float* __restrict__ x, unsigned short* __restrict__ xb) {
    const int wv = threadIdx.x >> 6, lane = threadIdx.x & 63;
    const int stride = gridDim.x * 4;
    for (int row = blockIdx.x * 4 + wv; row < 131072; row += stride) {
        const float* xr = x + (long)row * 1024;
        f32x4 v[4];
        float s = 0.f;
#pragma unroll
        for (int c = 0; c < 4; ++c) {
            v[c] = *(const f32x4*)(xr + c * 256 + lane * 4);
            s += v[c].x * v[c].x + v[c].y * v[c].y + v[c].z * v[c].z + v[c].w * v[c].w;
        }
#pragma unroll
        for (int off = 32; off > 0; off >>= 1) s += __shfl_xor(s, off, 64);
        float l = rsqrtf(s * (1.0f / 1024.0f));
        unsigned short* xo = xb + (long)row * 1024;
#pragma unroll
        for (int c = 0; c < 4; ++c) {
            bf16x4 b;
            b.x = (short)f2bf(v[c].x * l);
            b.y = (short)f2bf(v[c].y * l);
            b.z = (short)f2bf(v[c].z * l);
            b.w = (short)f2bf(v[c].w * l);
            *(bf16x4*)(xo + c * 256 + lane * 4) = b;
        }
    }
}

// ---------------------------------------------------------------------------
// Kernel 1: x3 = silu_gate(xb @ w12t^T). 256x256 tile, K=1024 -> 16 K-tiles.
// ---------------------------------------------------------------------------
__global__ __launch_bounds__(512, 2)
void gate_gemm(const unsigned short* __restrict__ xb,
               const unsigned short* __restrict__ w12t,
               unsigned short* __restrict__ x3) {
    __shared__ unsigned short lds[65536];    // 128 KB
    const int tid = threadIdx.x;
    const int lane = tid & 63;
    const int wv = tid >> 6;
    const int wr = wv >> 2, wcq = wv & 3;
    const int lhi = lane >> 4, llo = lane & 15;

    int bid = blockIdx.x;                    // 2048 blocks
    int wgid = (bid & 7) * 256 + (bid >> 3); // bijective XCD chunks
    const int mt = wgid >> 2, nt = wgid & 3;

    f32x4 acc[8][4];
#pragma unroll
    for (int i = 0; i < 8; ++i)
#pragma unroll
        for (int j = 0; j < 4; ++j) acc[i][j] = (f32x4){0.f, 0.f, 0.f, 0.f};

    gemm256<16>(xb + (long)mt * 256 * 1024, w12t + (long)nt * 256 * 1024,
                1024, lds, acc, tid);

    // ---- epilogue: pair even/odd interleaved cols (gate/up), SiLU, repack --
    // repack tile [256][136] ushorts (272B pitch)
#pragma unroll
    for (int ri = 0; ri < 8; ++ri)
#pragma unroll
        for (int rr = 0; rr < 4; ++rr) {
            int R = wr * 128 + ri * 16 + lhi * 4 + rr;
#pragma unroll
            for (int cj = 0; cj < 4; ++cj) {
                float v = acc[ri][cj][rr];
                float p = __shfl_xor(v, 1, 64);
                float g = (lane & 1) ? p : v;
                float u = (lane & 1) ? v : p;
                float s = (g / (1.0f + __expf(-g))) * u;
                if (!(lane & 1))
                    lds[R * 136 + wcq * 32 + cj * 8 + (llo >> 1)] = f2bf(s);
            }
        }
    __syncthreads();
    unsigned short* xg = x3 + (long)(mt * 256) * 512 + nt * 128;
#pragma unroll
    for (int i = 0; i < 8; ++i) {
        int c = i * 512 + tid;               // 4096 chunks of 16B
        int row = c >> 4, ch = c & 15;
        *(bf16x8*)(xg + (long)row * 512 + ch * 8) = *(const bf16x8*)&lds[row * 136 + ch * 8];
    }
}

// ---------------------------------------------------------------------------
// Kernel 2: out = x3 @ w3t (M x 1024 fp32). 256x256 tile, K=512 -> 8 K-tiles.
// ---------------------------------------------------------------------------
__global__ __launch_bounds__(512, 2)
void down_gemm(const unsigned short* __restrict__ x3,
               const unsigned short* __restrict__ w3t,
               float* __restrict__ out) {
    __shared__ unsigned short lds[65536];
    const int tid = threadIdx.x;
    const int lane = tid & 63;
    const int wv = tid >> 6;
    const int wr = wv >> 2, wcq = wv & 3;
    const int lhi = lane >> 4, llo = lane & 15;

    int bid = blockIdx.x;                    // 2048 blocks
    int wgid = (bid & 7) * 256 + (bid >> 3);
    const int mt = wgid >> 2, nt = wgid & 3;

    f32x4 acc[8][4];
#pragma unroll
    for (int i = 0; i < 8; ++i)
#pragma unroll
        for (int j = 0; j < 4; ++j) acc[i][j] = (f32x4){0.f, 0.f, 0.f, 0.f};

    gemm256<8>(x3 + (long)mt * 256 * 512, w3t + (long)nt * 256 * 512,
               512, lds, acc, tid);

    float* op = out + (long)(mt * 256) * 1024 + nt * 256;
#pragma unroll
    for (int ri = 0; ri < 8; ++ri)
#pragma unroll
        for (int rr = 0; rr < 4; ++rr) {
            int R = wr * 128 + ri * 16 + lhi * 4 + rr;
#pragma unroll
            for (int cj = 0; cj < 4; ++cj)
                op[(long)R * 1024 + wcq * 64 + cj * 16 + llo] = acc[ri][cj][rr];
        }
}

// ---------------------------------------------------------------------------
extern "C" void kernel_launch(void* const* d_in, const int* in_sizes, int n_in,
                              void* d_out, int out_size, void* d_ws, size_t ws_size,
                              hipStream_t stream) {
    const float* x  = (const float*)d_in[0];
    const float* w0 = (const float*)d_in[1];
    const float* w1 = (const float*)d_in[2];
    const float* w2 = (const float*)d_in[3];
    const float* w3 = (const float*)d_in[4];
    float* out = (float*)d_out;

    unsigned short* w12t = (unsigned short*)d_ws;           // 2MB
    unsigned short* w3t  = w12t + 1024 * 1024;              // 1MB
    unsigned short* x3   = w3t + 1024 * 512;                // 128MB
    unsigned short* xb   = x3 + (size_t)131072 * 512;       // 256MB

    prep_w<<<dim3(6144), dim3(256), 0, stream>>>(w0, w1, w2, w3, w12t, w3t);
    prep_x<<<dim3(2048), dim3(256), 0, stream>>>(x, xb);
    gate_gemm<<<dim3(2048), dim3(512), 0, stream>>>(xb, w12t, x3);
    down_gemm<<<dim3(2048), dim3(512), 0, stream>>>(x3, w3t, out);
}

// Round 8
// 697.733 us; speedup vs baseline: 1.0182x; 1.0182x over previous
//
#include <hip/hip_runtime.h>
#include <cstdint>

typedef __attribute__((ext_vector_type(4))) float f32x4;
typedef __attribute__((ext_vector_type(8))) short bf16x8;
typedef __attribute__((ext_vector_type(4))) short bf16x4;

#define DEV static __device__ __forceinline__

// round-to-nearest-even f32 -> bf16 (bit pattern)
DEV unsigned short f2bf(float f) {
    union { float f; unsigned int u; } v; v.f = f;
    unsigned int u = v.u;
    return (unsigned short)((u + 0x7FFFu + ((u >> 16) & 1u)) >> 16);
}

// async global->LDS 16B per lane; LDS dest = wave-uniform base + lane*16
DEV void async_cp16(const void* g, void* l) {
    __builtin_amdgcn_global_load_lds(
        (const __attribute__((address_space(1))) unsigned int*)g,
        (__attribute__((address_space(3))) unsigned int*)l,
        16, 0, 0);
}

// stage one 128x64 bf16 half-tile (16KB): 512 threads x 2 chunks of 16B.
// linear LDS dest, inverse-swizzled global source (involution: slot^=(row&7)).
DEV void stage_half(const unsigned short* __restrict__ g, long kofs,
                    unsigned short* l, int tid, int gpitch) {
#pragma unroll
    for (int i = 0; i < 2; ++i) {
        int c = i * 512 + tid;
        int row = c >> 3;
        int ss = (c & 7) ^ (row & 7);
        async_cp16(g + (long)row * gpitch + kofs + ss * 8,
                   l + (i * 512 + (tid & 448)) * 8);
    }
}

// swizzled LDS fragment read (bank-conflict-free pair of the stage swizzle)
DEV bf16x8 ldsrd(const unsigned short* base, int r, int q) {
    return *(const bf16x8*)&base[r * 64 + ((q ^ (r & 7)) << 3)];
}

// ---------------------------------------------------------------------------
// 256x256 8-wave GEMM core, m201-style 8-phase lockstep. BK=64, NT K-tiles
// (NT even), dbuf'd 128KB LDS.
// lds layout (ushort idx): A(d,h) = (d*2+h)*8192 ; B(d,h) = 32768+(d*2+h)*8192
// Wave (wr=wv>>2, wcq=wv&3) owns C rows [wr*128,+128) x cols [wcq*64,+64).
// Iteration = 2 K-tiles: E=2it (buf0, ph0-3), O=2it+1 (buf1, ph4-7); all LDS
// bases compile-time. Each phase: {ds_read this phase's frags; stage 1
// half-tile; s_barrier; lgkmcnt(0); setprio(1); 16 MFMA; setprio(0);
// s_barrier}. Stage order: ph0-2 -> O.h1,h2,h3(buf1); ph3 -> E2.h0(buf0);
// ph4-6 -> E2.h1,h2,h3; ph7 -> O2.h0(buf1). Counted gates at end of ph3/ph7:
// vmcnt(2) (outstanding=10, oldest 8 = the tile read next; 2 newest stay in
// flight). Tail: vmcnt(0) at last-iter ph3; no gate at last ph7.
// Race ledger: a stage into a buffer is issued only after a barrier-pair
// that postdates all waves' lgkm(0)-drained reads of that buffer.
// ---------------------------------------------------------------------------
template <int NT>
DEV void gemm256(const unsigned short* __restrict__ gA,
                 const unsigned short* __restrict__ gB,
                 const int gpitch, unsigned short* lds,
                 f32x4 (&acc)[8][4], const int tid) {
    const int lane = tid & 63;
    const int wv = tid >> 6;
    const int wr = wv >> 2;
    const int wcq = wv & 3;
    const int lhi = lane >> 4, llo = lane & 15;
    const int hb = wcq >> 1;           // B half-tile index
    const int br0 = (wcq & 1) * 64;    // B row base within half

    const unsigned short* lA0 = lds + (0 * 2 + wr) * 8192;           // buf0 A
    const unsigned short* lA1 = lds + (1 * 2 + wr) * 8192;           // buf1 A
    const unsigned short* lB0 = lds + 32768 + (0 * 2 + hb) * 8192;   // buf0 B
    const unsigned short* lB1 = lds + 32768 + (1 * 2 + hb) * 8192;   // buf1 B

#define MG(AF, BF, RI0, CJ0)                                                  \
    _Pragma("unroll") for (int kq = 0; kq < 2; ++kq)                          \
    _Pragma("unroll") for (int i = 0; i < 4; ++i)                             \
    _Pragma("unroll") for (int j = 0; j < 2; ++j)                             \
        acc[RI0 + i][CJ0 + j] = __builtin_amdgcn_mfma_f32_16x16x32_bf16(      \
            AF[kq][i], BF[kq][j], acc[RI0 + i][CJ0 + j], 0, 0, 0);

#define RD_AF0(L) _Pragma("unroll") for (int kq = 0; kq < 2; ++kq)            \
    _Pragma("unroll") for (int i = 0; i < 4; ++i)                             \
        af0[kq][i] = ldsrd(L, i * 16 + llo, kq * 4 + lhi);
#define RD_AF1(L) _Pragma("unroll") for (int kq = 0; kq < 2; ++kq)            \
    _Pragma("unroll") for (int i = 0; i < 4; ++i)                             \
        af1[kq][i] = ldsrd(L, 64 + i * 16 + llo, kq * 4 + lhi);
#define RD_BF0(L) _Pragma("unroll") for (int kq = 0; kq < 2; ++kq)            \
    _Pragma("unroll") for (int j = 0; j < 2; ++j)                             \
        bf0[kq][j] = ldsrd(L, br0 + j * 16 + llo, kq * 4 + lhi);
#define RD_BF1(L) _Pragma("unroll") for (int kq = 0; kq < 2; ++kq)            \
    _Pragma("unroll") for (int j = 0; j < 2; ++j)                             \
        bf1[kq][j] = ldsrd(L, br0 + 32 + j * 16 + llo, kq * 4 + lhi);

#define SA0(BUF, K) stage_half(gA, K, lds + ((BUF) * 2 + 0) * 8192, tid, gpitch);
#define SA1(BUF, K) stage_half(gA + (long)128 * gpitch, K, lds + ((BUF) * 2 + 1) * 8192, tid, gpitch);
#define SB0(BUF, K) stage_half(gB, K, lds + 32768 + ((BUF) * 2 + 0) * 8192, tid, gpitch);
#define SB1(BUF, K) stage_half(gB + (long)128 * gpitch, K, lds + 32768 + ((BUF) * 2 + 1) * 8192, tid, gpitch);

#define BAR __builtin_amdgcn_s_barrier();
#define SCB __builtin_amdgcn_sched_barrier(0);
#define LGKM0 asm volatile("s_waitcnt lgkmcnt(0)");
#define P1 __builtin_amdgcn_s_setprio(1);
#define P0 __builtin_amdgcn_s_setprio(0);
#define VM2 asm volatile("s_waitcnt vmcnt(2)" ::: "memory");
#define VM0 asm volatile("s_waitcnt vmcnt(0)" ::: "memory");

    // prologue = virtual iter(-1) ph3-7: tile0 h0-h3 -> buf0, tile1 h0 -> buf1
    SA0(0, 0) SA1(0, 0) SB0(0, 0) SB1(0, 0)
    SA0(1, 64)
    VM2
    BAR

    bf16x8 af0[2][4], af1[2][4], bf0[2][2], bf1[2][2];

    for (int it = 0; it < NT / 2; ++it) {
        const long kO  = (long)(2 * it + 1) * 64;
        const long kE2 = (long)(2 * it + 2) * 64;
        const long kO2 = (long)(2 * it + 3) * 64;
        const bool pf = (it + 1 < NT / 2);

        // ================= tile E (buf0) =================
        // ph0
        RD_AF0(lA0) RD_BF0(lB0)
        SA1(1, kO)
        BAR LGKM0 SCB
        P1 MG(af0, bf0, 0, 0) P0
        BAR
        // ph1
        RD_BF1(lB0)
        SB0(1, kO)
        BAR LGKM0 SCB
        P1 MG(af0, bf1, 0, 2) P0
        BAR
        // ph2
        RD_AF1(lA0)
        SB1(1, kO)
        BAR LGKM0 SCB
        P1 MG(af1, bf0, 4, 0) P0
        BAR
        // ph3 (gate)
        if (pf) { SA0(0, kE2) }
        BAR
        P1 MG(af1, bf1, 4, 2) P0
        if (pf) { VM2 } else { VM0 }
        BAR SCB

        // ================= tile O (buf1) =================
        // ph4
        RD_AF0(lA1) RD_BF0(lB1)
        if (pf) { SA1(0, kE2) }
        BAR LGKM0 SCB
        P1 MG(af0, bf0, 0, 0) P0
        BAR
        // ph5
        RD_BF1(lB1)
        if (pf) { SB0(0, kE2) }
        BAR LGKM0 SCB
        P1 MG(af0, bf1, 0, 2) P0
        BAR
        // ph6
        RD_AF1(lA1)
        if (pf) { SB1(0, kE2) }
        BAR LGKM0 SCB
        P1 MG(af1, bf0, 4, 0) P0
        BAR
        // ph7 (gate)
        if (pf) { SA0(1, kO2) }
        BAR
        P1 MG(af1, bf1, 4, 2) P0
        if (pf) { VM2 }
        BAR SCB
    }
#undef MG
#undef RD_AF0
#undef RD_AF1
#undef RD_BF0
#undef RD_BF1
#undef SA0
#undef SA1
#undef SB0
#undef SB1
#undef BAR
#undef SCB
#undef LGKM0
#undef P1
#undef P0
#undef VM2
#undef VM0
}

// ---------------------------------------------------------------------------
// Kernel 0: weight prep.
//  w12t[n][k]: n even -> bf16(w0[k]*w1[k][n/2]), n odd -> bf16(w0[k]*w2[k][n/2])
//  w3t[j][n] = bf16(w3[n][j])   (1024 x 512, n contiguous)
// ---------------------------------------------------------------------------
__global__ void prep_w(const float* __restrict__ w0, const float* __restrict__ w1,
                       const float* __restrict__ w2, const float* __restrict__ w3,
                       unsigned short* __restrict__ w12t, unsigned short* __restrict__ w3t) {
    int t = blockIdx.x * 256 + threadIdx.x;
    if (t < 1048576) {
        int n = t >> 10, k = t & 1023;
        const float* src = (n & 1) ? w2 : w1;
        w12t[t] = f2bf(w0[k] * src[k * 512 + (n >> 1)]);
    } else {
        int idx = t - 1048576;
        int j = idx >> 9, n = idx & 511;
        w3t[idx] = f2bf(w3[n * 1024 + j]);
    }
}

// ---------------------------------------------------------------------------
// Kernel 0b: RMSNorm fold. xb[row][k] = bf16(x[row][k] * rsqrt(mean(x^2)))
// ---------------------------------------------------------------------------
__global__ __launch_bounds__(256)
void prep_x(const float* __restrict__ x, unsigned short* __restrict__ xb) {
    const int wv = threadIdx.x >> 6, lane = threadIdx.x & 63;
    const int stride = gridDim.x * 4;
    for (int row = blockIdx.x * 4 + wv; row < 131072; row += stride) {
        const float* xr = x + (long)row * 1024;
        f32x4 v[4];
        float s = 0.f;
#pragma unroll
        for (int c = 0; c < 4; ++c) {
            v[c] = *(const f32x4*)(xr + c * 256 + lane * 4);
            s += v[c].x * v[c].x + v[c].y * v[c].y + v[c].z * v[c].z + v[c].w * v[c].w;
        }
#pragma unroll
        for (int off = 32; off > 0; off >>= 1) s += __shfl_xor(s, off, 64);
        float l = rsqrtf(s * (1.0f / 1024.0f));
        unsigned short* xo = xb + (long)row * 1024;
#pragma unroll
        for (int c = 0; c < 4; ++c) {
            bf16x4 b;
            b.x = (short)f2bf(v[c].x * l);
            b.y = (short)f2bf(v[c].y * l);
            b.z = (short)f2bf(v[c].z * l);
            b.w = (short)f2bf(v[c].w * l);
            *(bf16x4*)(xo + c * 256 + lane * 4) = b;
        }
    }
}

// ---------------------------------------------------------------------------
// Kernel 1: x3 = silu_gate(xb @ w12t^T). 256x256 tile, K=1024 -> 16 K-tiles.
// ---------------------------------------------------------------------------
__global__ __launch_bounds__(512, 2)
void gate_gemm(const unsigned short* __restrict__ xb,
               const unsigned short* __restrict__ w12t,
               unsigned short* __restrict__ x3) {
    __shared__ unsigned short lds[65536];    // 128 KB
    const int tid = threadIdx.x;
    const int lane = tid & 63;
    const int wv = tid >> 6;
    const int wr = wv >> 2, wcq = wv & 3;
    const int lhi = lane >> 4, llo = lane & 15;

    int bid = blockIdx.x;                    // 2048 blocks
    int wgid = (bid & 7) * 256 + (bid >> 3); // bijective XCD chunks
    const int mt = wgid >> 2, nt = wgid & 3;

    f32x4 acc[8][4];
#pragma unroll
    for (int i = 0; i < 8; ++i)
#pragma unroll
        for (int j = 0; j < 4; ++j) acc[i][j] = (f32x4){0.f, 0.f, 0.f, 0.f};

    gemm256<16>(xb + (long)mt * 256 * 1024, w12t + (long)nt * 256 * 1024,
                1024, lds, acc, tid);

    // ---- epilogue: pair even/odd interleaved cols (gate/up), SiLU, repack --
    // repack tile [256][136] ushorts (272B pitch)
#pragma unroll
    for (int ri = 0; ri < 8; ++ri)
#pragma unroll
        for (int rr = 0; rr < 4; ++rr) {
            int R = wr * 128 + ri * 16 + lhi * 4 + rr;
#pragma unroll
            for (int cj = 0; cj < 4; ++cj) {
                float v = acc[ri][cj][rr];
                float p = __shfl_xor(v, 1, 64);
                float g = (lane & 1) ? p : v;
                float u = (lane & 1) ? v : p;
                float s = (g / (1.0f + __expf(-g))) * u;
                if (!(lane & 1))
                    lds[R * 136 + wcq * 32 + cj * 8 + (llo >> 1)] = f2bf(s);
            }
        }
    __syncthreads();
    unsigned short* xg = x3 + (long)(mt * 256) * 512 + nt * 128;
#pragma unroll
    for (int i = 0; i < 8; ++i) {
        int c = i * 512 + tid;               // 4096 chunks of 16B
        int row = c >> 4, ch = c & 15;
        *(bf16x8*)(xg + (long)row * 512 + ch * 8) = *(const bf16x8*)&lds[row * 136 + ch * 8];
    }
}

// ---------------------------------------------------------------------------
// Kernel 2: out = x3 @ w3t (M x 1024 fp32). 256x256 tile, K=512 -> 8 K-tiles.
// ---------------------------------------------------------------------------
__global__ __launch_bounds__(512, 2)
void down_gemm(const unsigned short* __restrict__ x3,
               const unsigned short* __restrict__ w3t,
               float* __restrict__ out) {
    __shared__ unsigned short lds[65536];
    const int tid = threadIdx.x;
    const int lane = tid & 63;
    const int wv = tid >> 6;
    const int wr = wv >> 2, wcq = wv & 3;
    const int lhi = lane >> 4, llo = lane & 15;

    int bid = blockIdx.x;                    // 2048 blocks
    int wgid = (bid & 7) * 256 + (bid >> 3);
    const int mt = wgid >> 2, nt = wgid & 3;

    f32x4 acc[8][4];
#pragma unroll
    for (int i = 0; i < 8; ++i)
#pragma unroll
        for (int j = 0; j < 4; ++j) acc[i][j] = (f32x4){0.f, 0.f, 0.f, 0.f};

    gemm256<8>(x3 + (long)mt * 256 * 512, w3t + (long)nt * 256 * 512,
               512, lds, acc, tid);

    float* op = out + (long)(mt * 256) * 1024 + nt * 256;
#pragma unroll
    for (int ri = 0; ri < 8; ++ri)
#pragma unroll
        for (int rr = 0; rr < 4; ++rr) {
            int R = wr * 128 + ri * 16 + lhi * 4 + rr;
#pragma unroll
            for (int cj = 0; cj < 4; ++cj)
                op[(long)R * 1024 + wcq * 64 + cj * 16 + llo] = acc[ri][cj][rr];
        }
}

// ---------------------------------------------------------------------------
extern "C" void kernel_launch(void* const* d_in, const int* in_sizes, int n_in,
                              void* d_out, int out_size, void* d_ws, size_t ws_size,
                              hipStream_t stream) {
    const float* x  = (const float*)d_in[0];
    const float* w0 = (const float*)d_in[1];
    const float* w1 = (const float*)d_in[2];
    const float* w2 = (const float*)d_in[3];
    const float* w3 = (const float*)d_in[4];
    float* out = (float*)d_out;

    unsigned short* w12t = (unsigned short*)d_ws;           // 2MB
    unsigned short* w3t  = w12t + 1024 * 1024;              // 1MB
    unsigned short* x3   = w3t + 1024 * 512;                // 128MB
    unsigned short* xb   = x3 + (size_t)131072 * 512;       // 256MB

    prep_w<<<dim3(6144), dim3(256), 0, stream>>>(w0, w1, w2, w3, w12t, w3t);
    prep_x<<<dim3(2048), dim3(256), 0, stream>>>(x, xb);
    gate_gemm<<<dim3(2048), dim3(512), 0, stream>>>(xb, w12t, x3);
    down_gemm<<<dim3(2048), dim3(512), 0, stream>>>(x3, w3t, out);
}